// Round 4
// baseline (398.993 us; speedup 1.0000x reference)
//
#include <hip/hip_runtime.h>
#include <hip/hip_bf16.h>

#define NBANK 131072
#define DF 1024
#define NB 64
#define NT (NBANK / 16)   // 8192 tiles of 16 rows
#define GRID 1024         // persistent blocks: 4/CU guaranteed resident, no tail
#define TPB (NT / GRID)   // 8 tiles per block

typedef float f32x4 __attribute__((ext_vector_type(4)));
typedef short bf16x8 __attribute__((ext_vector_type(8)));

__device__ __forceinline__ unsigned short f2bf(float f) {
    union { float f; unsigned u; } c; c.f = f;
    unsigned u = c.u;
    return (unsigned short)((u + 0x7FFFu + ((u >> 16) & 1u)) >> 16);
}

// Kernel A: L2-normalize the 64 input rows; emit x_f32, MFMA-ordered bf16
// A-fragments, and the per-tile update-row bitmask urs[8192]
// (tile = blockIdx.x*128 + threadIdx.x; NT = 64*128 exactly).
__global__ __launch_bounds__(128) void knorm(const float* __restrict__ inputs,
                                             const int* __restrict__ indexes,
                                             float* __restrict__ x_f32,
                                             bf16x8* __restrict__ xfrag,
                                             unsigned* __restrict__ urs) {
    int m = blockIdx.x;
    int t = threadIdx.x;          // handles k = t*8 .. t*8+7
    __shared__ float red[2];
    __shared__ int sidx[NB];
    if (t < NB) sidx[t] = indexes[t];
    const f32x4* row = (const f32x4*)(inputs + (size_t)m * DF);
    f32x4 v0 = row[t * 2];
    f32x4 v1 = row[t * 2 + 1];
    float s = v0.x*v0.x + v0.y*v0.y + v0.z*v0.z + v0.w*v0.w
            + v1.x*v1.x + v1.y*v1.y + v1.z*v1.z + v1.w*v1.w;
    for (int o = 32; o > 0; o >>= 1) s += __shfl_xor(s, o);
    if ((t & 63) == 0) red[t >> 6] = s;
    __syncthreads();
    float tot = red[0] + red[1];
    float inv = 1.0f / fmaxf(sqrtf(tot), 1e-12f);
    v0 *= inv; v1 *= inv;
    f32x4* xr = (f32x4*)(x_f32 + (size_t)m * DF);
    xr[t * 2]     = v0;
    xr[t * 2 + 1] = v1;
    unsigned short h[8] = { f2bf(v0.x), f2bf(v0.y), f2bf(v0.z), f2bf(v0.w),
                            f2bf(v1.x), f2bf(v1.y), f2bf(v1.z), f2bf(v1.w) };
    int idx = ((m >> 4) * 32 + (t >> 2)) * 64 + (t & 3) * 16 + (m & 15);
    xfrag[idx] = *(bf16x8*)h;
    // per-tile update mask
    int tile = m * 128 + t;
    int j0 = tile * 16;
    unsigned mask = 0;
#pragma unroll 8
    for (int j = 0; j < NB; ++j) {
        unsigned d = (unsigned)(sidx[j] - j0);
        if (d < 16u) mask |= (1u << d);
    }
    urs[tile] = mask;
}

// Kernel B: persistent, software-pipelined fused sim GEMM + bank copy +
// sequential momentum update. Per iteration (8 tiles/block):
//   phase A: consume regs v -> nontemporal outf copy + XOR-swizzled bf16 LDS
//   barrier1 = lgkmcnt(0)+s_barrier  (NO vmcnt drain -> stores stay in flight)
//   prefetch: issue next tile's 16-load burst (in flight across barriers)
//   phase B: pure ds_read+MFMA (A-fragments hoisted to 128 VGPRs once) + sim
//   barrier2 = s_barrier
//   phase C (rare): exact sequential momentum chain for owned update rows
__global__ __launch_bounds__(256, 5) void kmain(const float* __restrict__ features,
                                                const bf16x8* __restrict__ xfrag,
                                                const int* __restrict__ indexes,
                                                const float* __restrict__ x_f32,
                                                const unsigned* __restrict__ urs,
                                                float* __restrict__ sim,
                                                float* __restrict__ outf) {
    __shared__ __align__(16) unsigned char tile[32768];   // exactly 32KB -> 5 blocks/CU max
    int t = threadIdx.x;          // covers cols t*4 .. t*4+3 of each row
    int wave = t >> 6;
    int lane = t & 63;

    // hoist this wave's A fragments (M-tile = wave) for all 32 K-steps
    bf16x8 af[32];
#pragma unroll
    for (int ks = 0; ks < 32; ++ks)
        af[ks] = xfrag[(size_t)(wave * 32 + ks) * 64 + lane];

    unsigned bbase = (unsigned)(lane & 15) * 2048;
    unsigned bswz  = (unsigned)(lane & 7) << 4;           // (brow&7)<<4
    unsigned bcol  = (unsigned)(lane >> 4) * 16;
    int m0 = wave * 16 + (lane >> 4) * 4;

    int tileIdx = blockIdx.x;
    f32x4 v[16];
#pragma unroll
    for (int p = 0; p < 16; ++p)
        v[p] = *((const f32x4*)(features + (size_t)(tileIdx * 16 + p) * DF) + t);

    for (int it = 0; it < TPB; ++it) {
        int j0 = tileIdx * 16;
        unsigned urmask = urs[tileIdx];
        // phase A: consume v
#pragma unroll
        for (int p = 0; p < 16; ++p) {
            __builtin_nontemporal_store(v[p], (f32x4*)(outf + (size_t)(j0 + p) * DF) + t);
            unsigned lo = (unsigned)f2bf(v[p].x) | ((unsigned)f2bf(v[p].y) << 16);
            unsigned hi = (unsigned)f2bf(v[p].z) | ((unsigned)f2bf(v[p].w) << 16);
            uint2 pk; pk.x = lo; pk.y = hi;
            unsigned off = (unsigned)(p * 2048) + (((unsigned)(t * 8)) ^ ((unsigned)(p & 7) << 4));
            *(uint2*)(tile + off) = pk;
        }
        asm volatile("s_waitcnt lgkmcnt(0)\n\ts_barrier" ::: "memory");
        // prefetch next tile (stays in flight across barrier2)
        int nextIdx = tileIdx + GRID;
        if (it + 1 < TPB) {
#pragma unroll
            for (int p = 0; p < 16; ++p)
                v[p] = *((const f32x4*)(features + (size_t)(nextIdx * 16 + p) * DF) + t);
        }
        // phase B: MFMA (no VMEM reads)
        f32x4 acc = {0.f, 0.f, 0.f, 0.f};
#pragma unroll
        for (int ks = 0; ks < 32; ++ks) {
            bf16x8 b = *(const bf16x8*)(tile + bbase + (((unsigned)(ks * 64) + bcol) ^ bswz));
            acc = __builtin_amdgcn_mfma_f32_16x16x32_bf16(af[ks], b, acc, 0, 0, 0);
        }
#pragma unroll
        for (int r = 0; r < 4; ++r)
            __builtin_nontemporal_store(acc[r] * 20.0f,
                sim + (size_t)(m0 + r) * NBANK + j0 + (lane & 15));
        asm volatile("s_barrier" ::: "memory");
        // phase C: sequential momentum chain (uniform-rare; red aliased into tile,
        // safe: all waves are past barrier2; internal __syncthreads separate
        // red reads from next iteration's tile writes)
        if (urmask) {
            float* red = (float*)tile;
            for (int p = 0; p < 16; ++p) {
                if (!((urmask >> p) & 1)) continue;      // uniform
                int row = j0 + p;
                f32x4 cur = *((const f32x4*)(features + (size_t)row * DF) + t);
                for (int j = 0; j < NB; ++j) {
                    if (indexes[j] != row) continue;     // uniform
                    f32x4 xv = *((const f32x4*)(x_f32 + (size_t)j * DF) + t);
                    cur = cur * 0.2f + xv * 0.8f;
                    float s = cur.x*cur.x + cur.y*cur.y + cur.z*cur.z + cur.w*cur.w;
                    for (int o = 32; o > 0; o >>= 1) s += __shfl_xor(s, o);
                    if ((t & 63) == 0) red[t >> 6] = s;
                    __syncthreads();
                    float tot = red[0] + red[1] + red[2] + red[3];
                    __syncthreads();
                    float inv = 1.0f / fmaxf(sqrtf(tot), 1e-12f);
                    cur *= inv;
                }
                *((f32x4*)(outf + (size_t)row * DF) + t) = cur;
            }
        }
        tileIdx = nextIdx;
    }
}

extern "C" void kernel_launch(void* const* d_in, const int* in_sizes, int n_in,
                              void* d_out, int out_size, void* d_ws, size_t ws_size,
                              hipStream_t stream) {
    const float* inputs   = (const float*)d_in[0];
    const int*   indexes  = (const int*)d_in[1];
    const float* features = (const float*)d_in[2];
    float* sim  = (float*)d_out;                       // [64 * 131072]
    float* outf = sim + (size_t)NB * NBANK;            // [131072 * 1024]
    float*    x_f32 = (float*)d_ws;                                          // 256 KB
    bf16x8*   xfrag = (bf16x8*)((char*)d_ws + (size_t)NB * DF * 4);          // 128 KB
    unsigned* urs   = (unsigned*)((char*)d_ws + (size_t)NB * DF * 6);        // 32 KB

    knorm<<<NB, 128, 0, stream>>>(inputs, indexes, x_f32, xfrag, urs);
    kmain<<<GRID, 256, 0, stream>>>(features, xfrag, indexes, x_f32, urs, sim, outf);
}

// Round 5
// 231.525 us; speedup vs baseline: 1.7233x; 1.7233x over previous
//
#include <hip/hip_runtime.h>
#include <hip/hip_bf16.h>

#define NBANK 131072
#define DF 1024
#define NB 64

typedef float f32x4 __attribute__((ext_vector_type(4)));
typedef short bf16x8 __attribute__((ext_vector_type(8)));

__device__ __forceinline__ unsigned short f2bf(float f) {
    union { float f; unsigned u; } c; c.f = f;
    unsigned u = c.u;
    return (unsigned short)((u + 0x7FFFu + ((u >> 16) & 1u)) >> 16);
}

// Kernel A: L2-normalize the 64 input rows; emit x_f32 (f32, for the update
// chain), MFMA-lane-ordered bf16 A-fragments, and the per-tile update-row
// bitmask urs[8192] (tile = blockIdx.x*128 + threadIdx.x; 64*128 = 8192).
__global__ __launch_bounds__(128) void knorm(const float* __restrict__ inputs,
                                             const int* __restrict__ indexes,
                                             float* __restrict__ x_f32,
                                             bf16x8* __restrict__ xfrag,
                                             unsigned* __restrict__ urs) {
    int m = blockIdx.x;
    int t = threadIdx.x;          // handles k = t*8 .. t*8+7
    __shared__ float red[2];
    __shared__ int sidx[NB];
    if (t < NB) sidx[t] = indexes[t];
    const f32x4* row = (const f32x4*)(inputs + (size_t)m * DF);
    f32x4 v0 = row[t * 2];
    f32x4 v1 = row[t * 2 + 1];
    float s = v0.x*v0.x + v0.y*v0.y + v0.z*v0.z + v0.w*v0.w
            + v1.x*v1.x + v1.y*v1.y + v1.z*v1.z + v1.w*v1.w;
    for (int o = 32; o > 0; o >>= 1) s += __shfl_xor(s, o);
    if ((t & 63) == 0) red[t >> 6] = s;
    __syncthreads();
    float tot = red[0] + red[1];
    float inv = 1.0f / fmaxf(sqrtf(tot), 1e-12f);
    v0 *= inv; v1 *= inv;
    f32x4* xr = (f32x4*)(x_f32 + (size_t)m * DF);
    xr[t * 2]     = v0;
    xr[t * 2 + 1] = v1;
    unsigned short h[8] = { f2bf(v0.x), f2bf(v0.y), f2bf(v0.z), f2bf(v0.w),
                            f2bf(v1.x), f2bf(v1.y), f2bf(v1.z), f2bf(v1.w) };
    int idx = ((m >> 4) * 32 + (t >> 2)) * 64 + (t & 3) * 16 + (m & 15);
    xfrag[idx] = *(bf16x8*)h;
    // per-tile update-row mask
    int tile = m * 128 + t;
    int j0 = tile * 16;
    unsigned mask = 0;
#pragma unroll 8
    for (int j = 0; j < NB; ++j) {
        unsigned d = (unsigned)(sidx[j] - j0);
        if (d < 16u) mask |= (1u << d);
    }
    urs[tile] = mask;
}

// Kernel B: fused sim GEMM + bank copy + sequential momentum update.
// One 16-row tile per block (8192 blocks). Flow:
//   burst 16 global loads -> v[] (deep MLP)
//   phase A: bf16-pack v into XOR-swizzled LDS (no global stores yet)
//   barrier = lgkmcnt(0)+s_barrier   (loads consumed, no stores in flight ->
//                                     nothing drains; NO vmcnt wait)
//   phase B: issue 16 nontemporal outf copy-stores from v (overlap w/ MFMA),
//            then 4 waves x 32 K-steps mfma 16x16x32 bf16 -> sim
//   phase C (rare, urmask block-uniform): __syncthreads, then exact
//            sequential momentum chain; cur inits from v[p]; overwrites the
//            same thread's copy-store (program order => correct final value).
// LDS = exactly 32KB (red[] aliased into tile after the phase-C sync)
// -> 5 blocks/CU; ~80 live VGPRs under the (256,5) cap -> no spill.
__global__ __launch_bounds__(256, 5) void kmain(const float* __restrict__ features,
                                                const bf16x8* __restrict__ xfrag,
                                                const int* __restrict__ indexes,
                                                const float* __restrict__ x_f32,
                                                const unsigned* __restrict__ urs,
                                                float* __restrict__ sim,
                                                float* __restrict__ outf) {
    __shared__ __align__(16) unsigned char tile[32768];
    int t = threadIdx.x;          // covers cols t*4 .. t*4+3 of each row
    int j0 = blockIdx.x * 16;
    unsigned urmask = urs[blockIdx.x];

    // burst all 16 loads
    f32x4 v[16];
#pragma unroll
    for (int p = 0; p < 16; ++p)
        v[p] = *((const f32x4*)(features + (size_t)(j0 + p) * DF) + t);

    // phase A: bf16 pack -> swizzled LDS
#pragma unroll
    for (int p = 0; p < 16; ++p) {
        unsigned lo = (unsigned)f2bf(v[p].x) | ((unsigned)f2bf(v[p].y) << 16);
        unsigned hi = (unsigned)f2bf(v[p].z) | ((unsigned)f2bf(v[p].w) << 16);
        uint2 pk; pk.x = lo; pk.y = hi;
        unsigned off = (unsigned)(p * 2048) + (((unsigned)(t * 8)) ^ ((unsigned)(p & 7) << 4));
        *(uint2*)(tile + off) = pk;
    }
    asm volatile("s_waitcnt lgkmcnt(0)\n\ts_barrier" ::: "memory");

    // phase B: copy-stores (overlap with MFMA below)
#pragma unroll
    for (int p = 0; p < 16; ++p)
        __builtin_nontemporal_store(v[p], (f32x4*)(outf + (size_t)(j0 + p) * DF) + t);

    int wave = t >> 6;
    int lane = t & 63;
    const bf16x8* af = xfrag + (size_t)(wave * 32) * 64 + lane;
    unsigned bbase = (unsigned)(lane & 15) * 2048;
    unsigned bswz  = (unsigned)(lane & 7) << 4;
    unsigned bcol  = (unsigned)(lane >> 4) * 16;
    f32x4 acc = {0.f, 0.f, 0.f, 0.f};
#pragma unroll 8
    for (int ks = 0; ks < 32; ++ks) {
        bf16x8 a = af[ks * 64];
        bf16x8 b = *(const bf16x8*)(tile + bbase + (((unsigned)(ks * 64) + bcol) ^ bswz));
        acc = __builtin_amdgcn_mfma_f32_16x16x32_bf16(a, b, acc, 0, 0, 0);
    }
    int m0 = wave * 16 + (lane >> 4) * 4;
    int n = j0 + (lane & 15);
#pragma unroll
    for (int r = 0; r < 4; ++r)
        __builtin_nontemporal_store(acc[r] * 20.0f,
                                    sim + (size_t)(m0 + r) * NBANK + n);

    // phase C: sequential momentum chain (urmask is block-uniform)
    if (urmask) {
        __syncthreads();                 // all waves done reading tile
        float* red = (float*)tile;       // alias scratch into LDS
        for (int p = 0; p < 16; ++p) {
            if (!((urmask >> p) & 1)) continue;      // uniform
            int row = j0 + p;
            f32x4 cur = v[p];
            for (int j = 0; j < NB; ++j) {
                if (indexes[j] != row) continue;     // uniform
                f32x4 xv = *((const f32x4*)(x_f32 + (size_t)j * DF) + t);
                cur = cur * 0.2f + xv * 0.8f;
                float s = cur.x*cur.x + cur.y*cur.y + cur.z*cur.z + cur.w*cur.w;
                for (int o = 32; o > 0; o >>= 1) s += __shfl_xor(s, o);
                if ((t & 63) == 0) red[t >> 6] = s;
                __syncthreads();
                float tot = red[0] + red[1] + red[2] + red[3];
                __syncthreads();
                float inv = 1.0f / fmaxf(sqrtf(tot), 1e-12f);
                cur *= inv;
            }
            *((f32x4*)(outf + (size_t)row * DF) + t) = cur;
        }
    }
}

extern "C" void kernel_launch(void* const* d_in, const int* in_sizes, int n_in,
                              void* d_out, int out_size, void* d_ws, size_t ws_size,
                              hipStream_t stream) {
    const float* inputs   = (const float*)d_in[0];
    const int*   indexes  = (const int*)d_in[1];
    const float* features = (const float*)d_in[2];
    float* sim  = (float*)d_out;                       // [64 * 131072]
    float* outf = sim + (size_t)NB * NBANK;            // [131072 * 1024]
    float*    x_f32 = (float*)d_ws;                                          // 256 KB
    bf16x8*   xfrag = (bf16x8*)((char*)d_ws + (size_t)NB * DF * 4);          // 128 KB
    unsigned* urs   = (unsigned*)((char*)d_ws + (size_t)NB * DF * 6);        // 32 KB

    knorm<<<NB, 128, 0, stream>>>(inputs, indexes, x_f32, xfrag, urs);
    kmain<<<NBANK / 16, 256, 0, stream>>>(features, xfrag, indexes, x_f32, urs, sim, outf);
}

// Round 6
// 223.224 us; speedup vs baseline: 1.7874x; 1.0372x over previous
//
#include <hip/hip_runtime.h>
#include <hip/hip_bf16.h>

#define NBANK 131072
#define DF 1024
#define NB 64
#define PINROWS 61440   // rows < PINROWS loaded cacheable (240 MB pinned in 256 MB L3);
                        // rows >= PINROWS loaded nontemporal (stream, don't evict pin)

typedef float f32x4 __attribute__((ext_vector_type(4)));
typedef short bf16x8 __attribute__((ext_vector_type(8)));

__device__ __forceinline__ unsigned short f2bf(float f) {
    union { float f; unsigned u; } c; c.f = f;
    unsigned u = c.u;
    return (unsigned short)((u + 0x7FFFu + ((u >> 16) & 1u)) >> 16);
}

// Kernel A: L2-normalize the 64 input rows; emit x_f32 (f32, for the update
// chain), MFMA-lane-ordered bf16 A-fragments, and the per-tile update-row
// bitmask urs[8192] (tile = blockIdx.x*128 + threadIdx.x; 64*128 = 8192).
__global__ __launch_bounds__(128) void knorm(const float* __restrict__ inputs,
                                             const int* __restrict__ indexes,
                                             float* __restrict__ x_f32,
                                             bf16x8* __restrict__ xfrag,
                                             unsigned* __restrict__ urs) {
    int m = blockIdx.x;
    int t = threadIdx.x;          // handles k = t*8 .. t*8+7
    __shared__ float red[2];
    __shared__ int sidx[NB];
    if (t < NB) sidx[t] = indexes[t];
    const f32x4* row = (const f32x4*)(inputs + (size_t)m * DF);
    f32x4 v0 = row[t * 2];
    f32x4 v1 = row[t * 2 + 1];
    float s = v0.x*v0.x + v0.y*v0.y + v0.z*v0.z + v0.w*v0.w
            + v1.x*v1.x + v1.y*v1.y + v1.z*v1.z + v1.w*v1.w;
    for (int o = 32; o > 0; o >>= 1) s += __shfl_xor(s, o);
    if ((t & 63) == 0) red[t >> 6] = s;
    __syncthreads();
    float tot = red[0] + red[1];
    float inv = 1.0f / fmaxf(sqrtf(tot), 1e-12f);
    v0 *= inv; v1 *= inv;
    f32x4* xr = (f32x4*)(x_f32 + (size_t)m * DF);
    xr[t * 2]     = v0;
    xr[t * 2 + 1] = v1;
    unsigned short h[8] = { f2bf(v0.x), f2bf(v0.y), f2bf(v0.z), f2bf(v0.w),
                            f2bf(v1.x), f2bf(v1.y), f2bf(v1.z), f2bf(v1.w) };
    int idx = ((m >> 4) * 32 + (t >> 2)) * 64 + (t & 3) * 16 + (m & 15);
    xfrag[idx] = *(bf16x8*)h;
    // per-tile update-row mask
    int tile = m * 128 + t;
    int j0 = tile * 16;
    unsigned mask = 0;
#pragma unroll 8
    for (int j = 0; j < NB; ++j) {
        unsigned d = (unsigned)(sidx[j] - j0);
        if (d < 16u) mask |= (1u << d);
    }
    urs[tile] = mask;
}

// Kernel B: fused sim GEMM + bank copy + sequential momentum update.
// One 16-row tile per block (8192 blocks). Identical structure to R5 except:
//  - no min-waves launch bound (VGPR-unconstrained burst; LDS still caps
//    residency, and 4 blocks/CU measured == 5 blocks/CU)
//  - L3 pinning: blocks with j0 < PINROWS use plain cacheable loads (their
//    lines stay Infinity-Cache-resident across graph replays); blocks above
//    use nontemporal loads so the streaming tail doesn't evict the pin.
__global__ __launch_bounds__(256) void kmain(const float* __restrict__ features,
                                             const bf16x8* __restrict__ xfrag,
                                             const int* __restrict__ indexes,
                                             const float* __restrict__ x_f32,
                                             const unsigned* __restrict__ urs,
                                             float* __restrict__ sim,
                                             float* __restrict__ outf) {
    __shared__ __align__(16) unsigned char tile[32768];
    int t = threadIdx.x;          // covers cols t*4 .. t*4+3 of each row
    int j0 = blockIdx.x * 16;
    unsigned urmask = urs[blockIdx.x];

    // burst all 16 loads (block-uniform branch on pin region)
    f32x4 v[16];
    if (j0 < PINROWS) {
#pragma unroll
        for (int p = 0; p < 16; ++p)
            v[p] = *((const f32x4*)(features + (size_t)(j0 + p) * DF) + t);
    } else {
#pragma unroll
        for (int p = 0; p < 16; ++p)
            v[p] = __builtin_nontemporal_load((const f32x4*)(features + (size_t)(j0 + p) * DF) + t);
    }

    // phase A: bf16 pack -> swizzled LDS
#pragma unroll
    for (int p = 0; p < 16; ++p) {
        unsigned lo = (unsigned)f2bf(v[p].x) | ((unsigned)f2bf(v[p].y) << 16);
        unsigned hi = (unsigned)f2bf(v[p].z) | ((unsigned)f2bf(v[p].w) << 16);
        uint2 pk; pk.x = lo; pk.y = hi;
        unsigned off = (unsigned)(p * 2048) + (((unsigned)(t * 8)) ^ ((unsigned)(p & 7) << 4));
        *(uint2*)(tile + off) = pk;
    }
    asm volatile("s_waitcnt lgkmcnt(0)\n\ts_barrier" ::: "memory");

    // phase B: copy-stores (overlap with MFMA below)
#pragma unroll
    for (int p = 0; p < 16; ++p)
        __builtin_nontemporal_store(v[p], (f32x4*)(outf + (size_t)(j0 + p) * DF) + t);

    int wave = t >> 6;
    int lane = t & 63;
    const bf16x8* af = xfrag + (size_t)(wave * 32) * 64 + lane;
    unsigned bbase = (unsigned)(lane & 15) * 2048;
    unsigned bswz  = (unsigned)(lane & 7) << 4;
    unsigned bcol  = (unsigned)(lane >> 4) * 16;
    f32x4 acc = {0.f, 0.f, 0.f, 0.f};
#pragma unroll 8
    for (int ks = 0; ks < 32; ++ks) {
        bf16x8 a = af[ks * 64];
        bf16x8 b = *(const bf16x8*)(tile + bbase + (((unsigned)(ks * 64) + bcol) ^ bswz));
        acc = __builtin_amdgcn_mfma_f32_16x16x32_bf16(a, b, acc, 0, 0, 0);
    }
    int m0 = wave * 16 + (lane >> 4) * 4;
    int n = j0 + (lane & 15);
#pragma unroll
    for (int r = 0; r < 4; ++r)
        __builtin_nontemporal_store(acc[r] * 20.0f,
                                    sim + (size_t)(m0 + r) * NBANK + n);

    // phase C: sequential momentum chain (urmask is block-uniform)
    if (urmask) {
        __syncthreads();                 // all waves done reading tile
        float* red = (float*)tile;       // alias scratch into LDS
        for (int p = 0; p < 16; ++p) {
            if (!((urmask >> p) & 1)) continue;      // uniform
            int row = j0 + p;
            f32x4 cur = v[p];
            for (int j = 0; j < NB; ++j) {
                if (indexes[j] != row) continue;     // uniform
                f32x4 xv = *((const f32x4*)(x_f32 + (size_t)j * DF) + t);
                cur = cur * 0.2f + xv * 0.8f;
                float s = cur.x*cur.x + cur.y*cur.y + cur.z*cur.z + cur.w*cur.w;
                for (int o = 32; o > 0; o >>= 1) s += __shfl_xor(s, o);
                if ((t & 63) == 0) red[t >> 6] = s;
                __syncthreads();
                float tot = red[0] + red[1] + red[2] + red[3];
                __syncthreads();
                float inv = 1.0f / fmaxf(sqrtf(tot), 1e-12f);
                cur *= inv;
            }
            *((f32x4*)(outf + (size_t)row * DF) + t) = cur;
        }
    }
}

extern "C" void kernel_launch(void* const* d_in, const int* in_sizes, int n_in,
                              void* d_out, int out_size, void* d_ws, size_t ws_size,
                              hipStream_t stream) {
    const float* inputs   = (const float*)d_in[0];
    const int*   indexes  = (const int*)d_in[1];
    const float* features = (const float*)d_in[2];
    float* sim  = (float*)d_out;                       // [64 * 131072]
    float* outf = sim + (size_t)NB * NBANK;            // [131072 * 1024]
    float*    x_f32 = (float*)d_ws;                                          // 256 KB
    bf16x8*   xfrag = (bf16x8*)((char*)d_ws + (size_t)NB * DF * 4);          // 128 KB
    unsigned* urs   = (unsigned*)((char*)d_ws + (size_t)NB * DF * 6);        // 32 KB

    knorm<<<NB, 128, 0, stream>>>(inputs, indexes, x_f32, xfrag, urs);
    kmain<<<NBANK / 16, 256, 0, stream>>>(features, xfrag, indexes, x_f32, urs, sim, outf);
}

// Round 7
// 201.109 us; speedup vs baseline: 1.9840x; 1.1100x over previous
//
#include <hip/hip_runtime.h>
#include <hip/hip_bf16.h>

#define NBANK 131072
#define DF 1024
#define NB 64

typedef float f32x4 __attribute__((ext_vector_type(4)));
typedef short bf16x8 __attribute__((ext_vector_type(8)));

__device__ __forceinline__ unsigned short f2bf(float f) {
    union { float f; unsigned u; } c; c.f = f;
    unsigned u = c.u;
    return (unsigned short)((u + 0x7FFFu + ((u >> 16) & 1u)) >> 16);
}

// Kernel A: L2-normalize the 64 input rows; emit x_f32 (f32, for the update
// chain), MFMA-lane-ordered bf16 A-fragments, and the per-tile update-row
// bitmask urs[8192] (tile = blockIdx.x*128 + threadIdx.x; 64*128 = 8192).
__global__ __launch_bounds__(128) void knorm(const float* __restrict__ inputs,
                                             const int* __restrict__ indexes,
                                             float* __restrict__ x_f32,
                                             bf16x8* __restrict__ xfrag,
                                             unsigned* __restrict__ urs) {
    int m = blockIdx.x;
    int t = threadIdx.x;          // handles k = t*8 .. t*8+7
    __shared__ float red[2];
    __shared__ int sidx[NB];
    if (t < NB) sidx[t] = indexes[t];
    const f32x4* row = (const f32x4*)(inputs + (size_t)m * DF);
    f32x4 v0 = row[t * 2];
    f32x4 v1 = row[t * 2 + 1];
    float s = v0.x*v0.x + v0.y*v0.y + v0.z*v0.z + v0.w*v0.w
            + v1.x*v1.x + v1.y*v1.y + v1.z*v1.z + v1.w*v1.w;
    for (int o = 32; o > 0; o >>= 1) s += __shfl_xor(s, o);
    if ((t & 63) == 0) red[t >> 6] = s;
    __syncthreads();
    float tot = red[0] + red[1];
    float inv = 1.0f / fmaxf(sqrtf(tot), 1e-12f);
    v0 *= inv; v1 *= inv;
    f32x4* xr = (f32x4*)(x_f32 + (size_t)m * DF);
    xr[t * 2]     = v0;
    xr[t * 2 + 1] = v1;
    unsigned short h[8] = { f2bf(v0.x), f2bf(v0.y), f2bf(v0.z), f2bf(v0.w),
                            f2bf(v1.x), f2bf(v1.y), f2bf(v1.z), f2bf(v1.w) };
    int idx = ((m >> 4) * 32 + (t >> 2)) * 64 + (t & 3) * 16 + (m & 15);
    xfrag[idx] = *(bf16x8*)h;
    // per-tile update-row mask
    int tile = m * 128 + t;
    int j0 = tile * 16;
    unsigned mask = 0;
#pragma unroll 8
    for (int j = 0; j < NB; ++j) {
        unsigned d = (unsigned)(sidx[j] - j0);
        if (d < 16u) mask |= (1u << d);
    }
    urs[tile] = mask;
}

// Kernel B: fused sim GEMM + bank copy + sequential momentum update.
// One 16-row tile per block (8192 blocks). Deep-MLP staging:
//   stage: 64 x global_load_lds (1 KB each) DMA the 64 KB f32 tile to LDS
//          with ZERO data VGPRs -> up to 128 KB/CU in flight (2 blocks/CU)
//   barrier (drains own vmcnt): tile complete
//   readback: each thread ds_reads its 16B column-chunk of all 16 rows into
//             v[16] (full-row linear reads: conflict-free)
//   barrier: f32 tile dead -> reuse LDS
//   pack: cvt v -> bf16, ds_write into the XOR-swizzled 32 KB bf16 tile
//   barrier (lgkm only in effect; no globals outstanding)
//   outf nt copy-stores issued HERE (fire-and-forget, overlap MFMA, never
//   drained by any later sync), then 4 waves x 32 K-step MFMA -> sim
//   phase C (rare): exact sequential momentum chain from v[p].
__global__ __launch_bounds__(256) void kmain(const float* __restrict__ features,
                                             const bf16x8* __restrict__ xfrag,
                                             const int* __restrict__ indexes,
                                             const float* __restrict__ x_f32,
                                             const unsigned* __restrict__ urs,
                                             float* __restrict__ sim,
                                             float* __restrict__ outf) {
    __shared__ __align__(16) unsigned char tile[65536];
    __shared__ float red[4];
    int t = threadIdx.x;          // owns within-row byte chunk t*16 .. t*16+15
    int wave = t >> 6;
    int lane = t & 63;
    int j0 = blockIdx.x * 16;
    unsigned urmask = urs[blockIdx.x];

    // stage: wave w DMAs rows 4w..4w+3 (4 x 1KB per row), linear LDS layout
#pragma unroll
    for (int rr = 0; rr < 4; ++rr) {
        int r = wave * 4 + rr;
        const char* g = (const char*)(features + (size_t)(j0 + r) * DF);
#pragma unroll
        for (int q = 0; q < 4; ++q)
            __builtin_amdgcn_global_load_lds(
                (const __attribute__((address_space(1))) void*)(g + q * 1024 + lane * 16),
                (__attribute__((address_space(3))) void*)(tile + r * 4096 + q * 1024),
                16, 0, 0);
    }
    __syncthreads();              // own vmcnt drained + barrier: tile complete

    // readback my column-chunk of every row
    f32x4 v[16];
#pragma unroll
    for (int p = 0; p < 16; ++p)
        v[p] = *(const f32x4*)(tile + p * 4096 + t * 16);
    __syncthreads();              // all reads done; LDS reusable

    // pack bf16 -> swizzled tile (no global stores yet)
#pragma unroll
    for (int p = 0; p < 16; ++p) {
        unsigned lo = (unsigned)f2bf(v[p].x) | ((unsigned)f2bf(v[p].y) << 16);
        unsigned hi = (unsigned)f2bf(v[p].z) | ((unsigned)f2bf(v[p].w) << 16);
        uint2 pk; pk.x = lo; pk.y = hi;
        unsigned off = (unsigned)(p * 2048) + (((unsigned)(t * 8)) ^ ((unsigned)(p & 7) << 4));
        *(uint2*)(tile + off) = pk;
    }
    __syncthreads();

    // outf copy-stores: issued after the last barrier -> never drained,
    // overlap with the MFMA phase below
#pragma unroll
    for (int p = 0; p < 16; ++p)
        __builtin_nontemporal_store(v[p], (f32x4*)(outf + (size_t)(j0 + p) * DF) + t);

    // MFMA phase (R6-proven loop)
    const bf16x8* af = xfrag + (size_t)(wave * 32) * 64 + lane;
    unsigned bbase = (unsigned)(lane & 15) * 2048;
    unsigned bswz  = (unsigned)(lane & 7) << 4;
    unsigned bcol  = (unsigned)(lane >> 4) * 16;
    f32x4 acc = {0.f, 0.f, 0.f, 0.f};
#pragma unroll 8
    for (int ks = 0; ks < 32; ++ks) {
        bf16x8 a = af[ks * 64];
        bf16x8 b = *(const bf16x8*)(tile + bbase + (((unsigned)(ks * 64) + bcol) ^ bswz));
        acc = __builtin_amdgcn_mfma_f32_16x16x32_bf16(a, b, acc, 0, 0, 0);
    }
    int m0 = wave * 16 + (lane >> 4) * 4;
    int n = j0 + (lane & 15);
#pragma unroll
    for (int r = 0; r < 4; ++r)
        __builtin_nontemporal_store(acc[r] * 20.0f,
                                    sim + (size_t)(m0 + r) * NBANK + n);

    // phase C: sequential momentum chain (urmask is block-uniform);
    // cur inits from v[p]; overwrites this thread's own copy-store
    // (same thread, same address -> program order gives the final value)
    if (urmask) {
        __syncthreads();
        for (int p = 0; p < 16; ++p) {
            if (!((urmask >> p) & 1)) continue;      // uniform
            int row = j0 + p;
            f32x4 cur = v[p];
            for (int j = 0; j < NB; ++j) {
                if (indexes[j] != row) continue;     // uniform
                f32x4 xv = *((const f32x4*)(x_f32 + (size_t)j * DF) + t);
                cur = cur * 0.2f + xv * 0.8f;
                float s = cur.x*cur.x + cur.y*cur.y + cur.z*cur.z + cur.w*cur.w;
                for (int o = 32; o > 0; o >>= 1) s += __shfl_xor(s, o);
                if ((t & 63) == 0) red[t >> 6] = s;
                __syncthreads();
                float tot = red[0] + red[1] + red[2] + red[3];
                __syncthreads();
                float inv = 1.0f / fmaxf(sqrtf(tot), 1e-12f);
                cur *= inv;
            }
            *((f32x4*)(outf + (size_t)row * DF) + t) = cur;
        }
    }
}

extern "C" void kernel_launch(void* const* d_in, const int* in_sizes, int n_in,
                              void* d_out, int out_size, void* d_ws, size_t ws_size,
                              hipStream_t stream) {
    const float* inputs   = (const float*)d_in[0];
    const int*   indexes  = (const int*)d_in[1];
    const float* features = (const float*)d_in[2];
    float* sim  = (float*)d_out;                       // [64 * 131072]
    float* outf = sim + (size_t)NB * NBANK;            // [131072 * 1024]
    float*    x_f32 = (float*)d_ws;                                          // 256 KB
    bf16x8*   xfrag = (bf16x8*)((char*)d_ws + (size_t)NB * DF * 4);          // 128 KB
    unsigned* urs   = (unsigned*)((char*)d_ws + (size_t)NB * DF * 6);        // 32 KB

    knorm<<<NB, 128, 0, stream>>>(inputs, indexes, x_f32, xfrag, urs);
    kmain<<<NBANK / 16, 256, 0, stream>>>(features, xfrag, indexes, x_f32, urs, sim, outf);
}